// Round 5
// baseline (84.325 us; speedup 1.0000x reference)
//
#include <hip/hip_runtime.h>
#include <math.h>
#include <stdint.h>

// Problem constants (FPModule: knn-interpolate + 2-layer MLP)
#define Bn    4
#define Nn    2048
#define Mn    8192
#define CIN   256
#define CSKIP 128
#define HID   256
#define COUT  128
#define KTOT  384   // CIN + CSKIP

typedef short bf16x8 __attribute__((ext_vector_type(8)));
typedef float f32x16 __attribute__((ext_vector_type(16)));

__device__ __forceinline__ ushort f2bf(float f) {
    union { float f; unsigned u; } v; v.f = f;
    return (ushort)((v.u + 0x7fffu + ((v.u >> 16) & 1u)) >> 16);   // RNE
}

// ---------------------------------------------------------------------------
// Kernel 1 (fused front): block roles by blockIdx.x:
//   [0,1024)      KNN: 32 queries/block, 8-way split scan, 2-pass top-3.
//   [1024,5120)   Abig[:,256:384] = bf16(x_skip)
//   [5120,5216)   W1T[n][k] = bf16(W1[k][n])
//   [5216,5248)   W2T[n][k] = bf16(W2[k][n])
//   [5248,5760)   tail: copy pos_skip + synthesize batch_skip into d_out
//
// KNN numerics: spos holds (2px,2py,2pz,pp). dot2 is BIT-IDENTICAL to 2*dot
// of the reference (x2 exact, rounding commutes with pow2 scaling), so
// d = (qq+pp) - dot2 matches reference d2 exactly. Selection:
//   pass1: per-chunk 3 smallest VALUES via med3/min net (exact, 3 inst/iter)
//   merge1: per-query 3rd-smallest value g3
//   pass2: rescan (identical d); rare-branch lex insert on d <= g3
//   merge2: lex (d, idx) insert over 24 slots == top_k value-then-index order
// ---------------------------------------------------------------------------
__global__ __launch_bounds__(256) void fused_front(
    const float* __restrict__ x,         // (B*N, CIN)
    const float* __restrict__ pos,       // (B*N, 3)
    const float* __restrict__ xs,        // (B*M, CSKIP)
    const float* __restrict__ pos_skip,  // (B*M, 3)
    const float* __restrict__ W1, const float* __restrict__ W2,
    ushort* __restrict__ Abig,           // (B*M, KTOT) bf16
    ushort* __restrict__ W1T, ushort* __restrict__ W2T,
    float* __restrict__ tail_dst)        // d_out + B*M*COUT
{
    __shared__ float4 spos[Nn];          // 32 KB: (2px,2py,2pz,pp)
    __shared__ float  sPd[8][3][33];     // pass1 values / pass2 match dists
    __shared__ int    sPi[8][3][33];     // pass2 match indices
    __shared__ float  sG[33];            // per-query 3rd-smallest
    __shared__ int    sIdx[32][3];
    __shared__ float  sW[32][4];

    const int bid = blockIdx.x;
    const int tid = threadIdx.x;

    if (bid >= 1024) {
        // ---------------- aux roles (no LDS use) ----------------
        const int cb = bid - 1024;
        if (cb < 4096) {
            const int q   = cb * 256 + tid;        // quad over 32768x128
            const int row = q >> 5;
            const int cq  = (q & 31) * 4;
            const float4 v = *(const float4*)(xs + (size_t)row * CSKIP + cq);
            ushort4 o; o.x = f2bf(v.x); o.y = f2bf(v.y); o.z = f2bf(v.z); o.w = f2bf(v.w);
            *(ushort4*)(Abig + (size_t)row * KTOT + CIN + cq) = o;
        } else if (cb < 4192) {
            const int q  = (cb - 4096) * 256 + tid;   // 24576 quads: n*96 + kq
            const int n  = q / 96;
            const int kq = (q % 96) * 4;
            ushort4 o;
            o.x = f2bf(W1[(size_t)(kq + 0) * HID + n]);
            o.y = f2bf(W1[(size_t)(kq + 1) * HID + n]);
            o.z = f2bf(W1[(size_t)(kq + 2) * HID + n]);
            o.w = f2bf(W1[(size_t)(kq + 3) * HID + n]);
            *(ushort4*)(W1T + (size_t)n * KTOT + kq) = o;
        } else if (cb < 4224) {
            const int q  = (cb - 4192) * 256 + tid;   // 8192 quads: n*64 + kq
            const int n  = q >> 6;
            const int kq = (q & 63) * 4;
            ushort4 o;
            o.x = f2bf(W2[(size_t)(kq + 0) * COUT + n]);
            o.y = f2bf(W2[(size_t)(kq + 1) * COUT + n]);
            o.z = f2bf(W2[(size_t)(kq + 2) * COUT + n]);
            o.w = f2bf(W2[(size_t)(kq + 3) * COUT + n]);
            *(ushort4*)(W2T + (size_t)n * HID + kq) = o;
        } else {
            const int i = (cb - 4224) * 256 + tid;
            const int nPos = Bn * Mn * 3;             // 98304
            if (i < nPos) tail_dst[i] = pos_skip[i];
            else          tail_dst[i] = (float)((i - nPos) >> 13);
        }
        return;
    }

    // ---------------- KNN role ----------------
    const int qloc   = tid & 31;
    const int chunk  = tid >> 5;
    const int blockQ = bid * 32;
    const int b      = blockQ / Mn;

    for (int i = tid; i < Nn; i += 256) {
        const float* p = pos + (size_t)(b * Nn + i) * 3;
        float p0 = p[0], p1 = p[1], p2 = p[2];
        float pp = __fadd_rn(__fadd_rn(__fmul_rn(p0, p0), __fmul_rn(p1, p1)),
                             __fmul_rn(p2, p2));
        spos[i] = make_float4(2.0f * p0, 2.0f * p1, 2.0f * p2, pp);
    }
    __syncthreads();

    const int q = blockQ + qloc;
    const float* qp = pos_skip + (size_t)q * 3;
    const float q0 = qp[0], q1 = qp[1], q2 = qp[2];
    const float qq = __fadd_rn(__fadd_rn(__fmul_rn(q0, q0), __fmul_rn(q1, q1)),
                               __fmul_rn(q2, q2));
    const int base = chunk * 256;

    // ---- pass 1: 3 smallest distances (values only), med3/min net ----
    {
        float v1 = INFINITY, v2 = INFINITY, v3 = INFINITY;
#pragma unroll 8
        for (int j = 0; j < 256; ++j) {
            const float4 P = spos[base + j];
            const float dot2 = __fadd_rn(__fadd_rn(__fmul_rn(q0, P.x), __fmul_rn(q1, P.y)),
                                         __fmul_rn(q2, P.z));
            const float d = __fsub_rn(__fadd_rn(qq, P.w), dot2);
            v3 = __builtin_amdgcn_fmed3f(d, v2, v3);   // uses OLD v2
            v2 = __builtin_amdgcn_fmed3f(d, v1, v2);   // uses OLD v1
            v1 = fminf(v1, d);
        }
        sPd[chunk][0][qloc] = v1; sPd[chunk][1][qloc] = v2; sPd[chunk][2][qloc] = v3;
    }
    __syncthreads();

    // ---- merge 1: per-query global 3rd-smallest value g3 ----
    if (tid < 32) {
        float g1 = INFINITY, g2 = INFINITY, g3 = INFINITY;
#pragma unroll
        for (int c = 0; c < 8; ++c)
#pragma unroll
            for (int s = 0; s < 3; ++s) {
                const float d = sPd[c][s][tid];
                g3 = __builtin_amdgcn_fmed3f(d, g2, g3);
                g2 = __builtin_amdgcn_fmed3f(d, g1, g2);
                g1 = fminf(g1, d);
            }
        sG[tid] = g3;
    }
    __syncthreads();

    // ---- pass 2: recover indices; rare-branch lex insert on d <= g3 ----
    {
        const float g3 = sG[qloc];
        float md0 = INFINITY, md1 = INFINITY, md2 = INFINITY;
        int   mi0 = 0, mi1 = 0, mi2 = 0;
#pragma unroll 4
        for (int j = 0; j < 256; ++j) {
            const float4 P = spos[base + j];
            const float dot2 = __fadd_rn(__fadd_rn(__fmul_rn(q0, P.x), __fmul_rn(q1, P.y)),
                                         __fmul_rn(q2, P.z));
            const float d = __fsub_rn(__fadd_rn(qq, P.w), dot2);
            if (d <= g3) {       // rare (~3 matches / 256 iters per thread)
                const int idx = base + j;
                const bool c1 = d < md0, c2 = d < md1, c3 = d < md2;
                md2 = c3 ? (c2 ? md1 : d) : md2;  mi2 = c3 ? (c2 ? mi1 : idx) : mi2;
                md1 = c2 ? (c1 ? md0 : d) : md1;  mi1 = c2 ? (c1 ? mi0 : idx) : mi1;
                md0 = c1 ? d : md0;               mi0 = c1 ? idx : mi0;
            }
        }
        __syncthreads();   // merge1 done reading sPd before overwrite
        sPd[chunk][0][qloc] = md0; sPd[chunk][1][qloc] = md1; sPd[chunk][2][qloc] = md2;
        sPi[chunk][0][qloc] = mi0; sPi[chunk][1][qloc] = mi1; sPi[chunk][2][qloc] = mi2;
    }
    __syncthreads();

    // ---- merge 2: lex (d, idx) top-3 over 24 slots == top_k order ----
    if (tid < 32) {
        float mA = INFINITY, mB = INFINITY, mC = INFINITY;
        int   jA = 0x7fffffff, jB = 0x7fffffff, jC = 0x7fffffff;
#pragma unroll
        for (int c = 0; c < 8; ++c)
#pragma unroll
            for (int s = 0; s < 3; ++s) {
                const float d = sPd[c][s][tid];
                const int   i = sPi[c][s][tid];
                const bool b1 = (d < mA) || (d == mA && i < jA);
                const bool b2 = (d < mB) || (d == mB && i < jB);
                const bool b3 = (d < mC) || (d == mC && i < jC);
                mC = b3 ? (b2 ? mB : d) : mC;  jC = b3 ? (b2 ? jB : i) : jC;
                mB = b2 ? (b1 ? mA : d) : mB;  jB = b2 ? (b1 ? jA : i) : jB;
                mA = b1 ? d : mA;              jA = b1 ? i : jA;
            }
        const float w0 = 1.0f / (fmaxf(mA, 0.0f) + 1e-16f);
        const float w1 = 1.0f / (fmaxf(mB, 0.0f) + 1e-16f);
        const float w2 = 1.0f / (fmaxf(mC, 0.0f) + 1e-16f);
        sIdx[tid][0] = jA; sIdx[tid][1] = jB; sIdx[tid][2] = jC;
        sW[tid][0] = w0; sW[tid][1] = w1; sW[tid][2] = w2;
        sW[tid][3] = w0 + w1 + w2;
    }
    __syncthreads();

    // gather: wave w handles queries [w*8, w*8+8); lane covers 4 channels
    const int wave = tid >> 6, lane = tid & 63;
    const size_t xbase = (size_t)b * Nn * CIN;
    for (int j = 0; j < 8; ++j) {
        const int lq = wave * 8 + j;
        const int gq = blockQ + lq;
        const int i0 = sIdx[lq][0], i1 = sIdx[lq][1], i2 = sIdx[lq][2];
        const float w0 = sW[lq][0], w1 = sW[lq][1], w2 = sW[lq][2], den = sW[lq][3];
        const float4 f0 = ((const float4*)(x + xbase + (size_t)i0 * CIN))[lane];
        const float4 f1 = ((const float4*)(x + xbase + (size_t)i1 * CIN))[lane];
        const float4 f2 = ((const float4*)(x + xbase + (size_t)i2 * CIN))[lane];
        ushort4 ov;
        ov.x = f2bf((w0 * f0.x + w1 * f1.x + w2 * f2.x) / den);
        ov.y = f2bf((w0 * f0.y + w1 * f1.y + w2 * f2.y) / den);
        ov.z = f2bf((w0 * f0.z + w1 * f1.z + w2 * f2.z) / den);
        ov.w = f2bf((w0 * f0.w + w1 * f1.w + w2 * f2.w) / den);
        *(ushort4*)(Abig + (size_t)gq * KTOT + lane * 4) = ov;
    }
}

// ---------------------------------------------------------------------------
// Kernel 2: fused MLP via bf16 MFMA (32x32x16), f32 accum. (unchanged)
// ---------------------------------------------------------------------------
__global__ __launch_bounds__(256, 1) void mlp_fused(
    const ushort* __restrict__ Abig,   // [32768][384] bf16
    const ushort* __restrict__ W1T,    // [256][384] bf16
    const float*  __restrict__ b1,
    const ushort* __restrict__ W2T,    // [128][256] bf16
    const float*  __restrict__ b2,
    float* __restrict__ out)           // [32768][128] f32
{
    __shared__ ushort Ast[128 * 32];   // 8 KB
    __shared__ ushort Bst[128 * 32];   // 8 KB
    __shared__ ushort Hs [128 * 128];  // 32 KB

    const int tid  = threadIdx.x;
    const int wave = tid >> 6, lane = tid & 63;
    const int wr = wave >> 1, wc = wave & 1;      // 2x2 wave grid
    const int l31 = lane & 31, kc0 = lane >> 5;   // MFMA k-half
    const long rowbase = (long)blockIdx.x * 128;

    const int sr0 = tid >> 2;          // staging row (row+64 for 2nd chunk)
    const int ss0 = tid & 3;           // 16B slot
    const int ssw = (ss0 ^ (sr0 & 3)); // swizzled slot

    f32x16 acc2[2][2];
#pragma unroll
    for (int i = 0; i < 2; ++i)
#pragma unroll
        for (int j = 0; j < 2; ++j)
#pragma unroll
            for (int e = 0; e < 16; ++e) acc2[i][j][e] = 0.0f;

    for (int nh = 0; nh < 2; ++nh) {
        f32x16 acc1[2][2];
#pragma unroll
        for (int i = 0; i < 2; ++i)
#pragma unroll
            for (int j = 0; j < 2; ++j)
#pragma unroll
                for (int e = 0; e < 16; ++e) acc1[i][j][e] = 0.0f;

        const ushort* Ab = Abig + (size_t)rowbase * KTOT;
        const ushort* Wb = W1T + (size_t)(nh * 128) * KTOT;

        uint4 ra0, ra1, rb0, rb1;
        ra0 = *(const uint4*)(Ab + (size_t)sr0 * KTOT + ss0 * 8);
        ra1 = *(const uint4*)(Ab + (size_t)(sr0 + 64) * KTOT + ss0 * 8);
        rb0 = *(const uint4*)(Wb + (size_t)sr0 * KTOT + ss0 * 8);
        rb1 = *(const uint4*)(Wb + (size_t)(sr0 + 64) * KTOT + ss0 * 8);

        for (int t = 0; t < 12; ++t) {
            __syncthreads();
            *(uint4*)&Ast[sr0 * 32 + (ssw << 3)]        = ra0;
            *(uint4*)&Ast[(sr0 + 64) * 32 + (ssw << 3)] = ra1;
            *(uint4*)&Bst[sr0 * 32 + (ssw << 3)]        = rb0;
            *(uint4*)&Bst[(sr0 + 64) * 32 + (ssw << 3)] = rb1;
            __syncthreads();
            if (t < 11) {
                const int kt = (t + 1) * 32;
                ra0 = *(const uint4*)(Ab + (size_t)sr0 * KTOT + kt + ss0 * 8);
                ra1 = *(const uint4*)(Ab + (size_t)(sr0 + 64) * KTOT + kt + ss0 * 8);
                rb0 = *(const uint4*)(Wb + (size_t)sr0 * KTOT + kt + ss0 * 8);
                rb1 = *(const uint4*)(Wb + (size_t)(sr0 + 64) * KTOT + kt + ss0 * 8);
            }
#pragma unroll
            for (int s = 0; s < 2; ++s) {
                bf16x8 af[2], bq[2];
#pragma unroll
                for (int mf = 0; mf < 2; ++mf) {
                    const int r = wr * 64 + mf * 32 + l31;
                    af[mf] = *(const bf16x8*)&Ast[r * 32 + ((((s << 1) | kc0) ^ (r & 3)) << 3)];
                }
#pragma unroll
                for (int nf = 0; nf < 2; ++nf) {
                    const int rn = wc * 64 + nf * 32 + l31;
                    bq[nf] = *(const bf16x8*)&Bst[rn * 32 + ((((s << 1) | kc0) ^ (rn & 3)) << 3)];
                }
#pragma unroll
                for (int mf = 0; mf < 2; ++mf)
#pragma unroll
                    for (int nf = 0; nf < 2; ++nf)
                        acc1[mf][nf] = __builtin_amdgcn_mfma_f32_32x32x16_bf16(
                            af[mf], bq[nf], acc1[mf][nf], 0, 0, 0);
            }
        }

#pragma unroll
        for (int mf = 0; mf < 2; ++mf)
#pragma unroll
            for (int nf = 0; nf < 2; ++nf) {
                const int col = wc * 64 + nf * 32 + l31;
                const float b1v = b1[nh * 128 + col];
#pragma unroll
                for (int e = 0; e < 16; ++e) {
                    const int rl = wr * 64 + mf * 32 + (e & 3) + ((e >> 2) << 3) + (kc0 << 2);
                    const float hv = fmaxf(acc1[mf][nf][e] + b1v, 0.0f);
                    Hs[rl * 128 + (((col >> 3) ^ (rl & 7)) << 3) + (col & 7)] = f2bf(hv);
                }
            }
        __syncthreads();

        uint4 rw0, rw1;
        rw0 = *(const uint4*)(W2T + (size_t)sr0 * HID + nh * 128 + ss0 * 8);
        rw1 = *(const uint4*)(W2T + (size_t)(sr0 + 64) * HID + nh * 128 + ss0 * 8);

        for (int t = 0; t < 4; ++t) {
            __syncthreads();
            *(uint4*)&Bst[sr0 * 32 + (ssw << 3)]        = rw0;
            *(uint4*)&Bst[(sr0 + 64) * 32 + (ssw << 3)] = rw1;
            __syncthreads();
            if (t < 3) {
                const int kt = nh * 128 + (t + 1) * 32;
                rw0 = *(const uint4*)(W2T + (size_t)sr0 * HID + kt + ss0 * 8);
                rw1 = *(const uint4*)(W2T + (size_t)(sr0 + 64) * HID + kt + ss0 * 8);
            }
#pragma unroll
            for (int s = 0; s < 2; ++s) {
                bf16x8 af[2], bq[2];
#pragma unroll
                for (int mf = 0; mf < 2; ++mf) {
                    const int r  = wr * 64 + mf * 32 + l31;
                    const int kc = (t << 2) + (s << 1) + kc0;
                    af[mf] = *(const bf16x8*)&Hs[r * 128 + ((kc ^ (r & 7)) << 3)];
                }
#pragma unroll
                for (int nf = 0; nf < 2; ++nf) {
                    const int rn = wc * 64 + nf * 32 + l31;
                    bq[nf] = *(const bf16x8*)&Bst[rn * 32 + ((((s << 1) | kc0) ^ (rn & 3)) << 3)];
                }
#pragma unroll
                for (int mf = 0; mf < 2; ++mf)
#pragma unroll
                    for (int nf = 0; nf < 2; ++nf)
                        acc2[mf][nf] = __builtin_amdgcn_mfma_f32_32x32x16_bf16(
                            af[mf], bq[nf], acc2[mf][nf], 0, 0, 0);
            }
        }
        __syncthreads();
    }

#pragma unroll
    for (int mf = 0; mf < 2; ++mf)
#pragma unroll
        for (int nf = 0; nf < 2; ++nf) {
            const int col = wc * 64 + nf * 32 + l31;
            const float b2v = b2[col];
#pragma unroll
            for (int e = 0; e < 16; ++e) {
                const int rl = wr * 64 + mf * 32 + (e & 3) + ((e >> 2) << 3) + (kc0 << 2);
                out[(rowbase + rl) * COUT + col] = acc2[mf][nf][e] + b2v;
            }
        }
}

// ---------------------------------------------------------------------------
extern "C" void kernel_launch(void* const* d_in, const int* in_sizes, int n_in,
                              void* d_out, int out_size, void* d_ws, size_t ws_size,
                              hipStream_t stream)
{
    const float* x        = (const float*)d_in[0];
    const float* pos      = (const float*)d_in[1];
    const float* x_skip   = (const float*)d_in[2];
    const float* pos_skip = (const float*)d_in[3];
    const float* W1       = (const float*)d_in[4];
    const float* b1       = (const float*)d_in[5];
    const float* W2       = (const float*)d_in[6];
    const float* b2       = (const float*)d_in[7];

    float* out = (float*)d_out;

    // workspace: Abig (24MB) | W1T (192KB) | W2T (64KB)
    ushort* Abig = (ushort*)d_ws;
    ushort* W1T  = (ushort*)((char*)d_ws + (size_t)Bn * Mn * KTOT * 2);
    ushort* W2T  = (ushort*)((char*)W1T + (size_t)HID * KTOT * 2);

    // 1) fused front: KNN->Abig[:,0:256], x_skip->Abig[:,256:384], W1T/W2T, tail
    fused_front<<<dim3(1024 + 4224 + 512), 256, 0, stream>>>(
        x, pos, x_skip, pos_skip, W1, W2, Abig, W1T, W2T,
        out + (size_t)Bn * Mn * COUT);

    // 2) fused MLP: out = (relu([xi|x_skip] @ W1 + b1)) @ W2 + b2
    mlp_fused<<<dim3(Bn * Mn / 128), 256, 0, stream>>>(
        Abig, W1T, b1, W2T, b2, out);
}

// Round 6
// 82.515 us; speedup vs baseline: 1.0219x; 1.0219x over previous
//
#include <hip/hip_runtime.h>
#include <math.h>
#include <stdint.h>

// Problem constants (FPModule: knn-interpolate + 2-layer MLP)
#define Bn    4
#define Nn    2048
#define Mn    8192
#define CIN   256
#define CSKIP 128
#define HID   256
#define COUT  128
#define KTOT  384   // CIN + CSKIP

typedef short bf16x8 __attribute__((ext_vector_type(8)));
typedef float f32x16 __attribute__((ext_vector_type(16)));

__device__ __forceinline__ ushort f2bf(float f) {
    union { float f; unsigned u; } v; v.f = f;
    return (ushort)((v.u + 0x7fffu + ((v.u >> 16) & 1u)) >> 16);   // RNE
}

// ---------------------------------------------------------------------------
// Kernel A: pack pos -> pos4 = (2px, 2py, 2pz, pp).  8192 points, 32 blocks.
// pp computed with explicit _rn ops (matches reference); 2x is exact so the
// inner-loop dot2 is bit-identical to 2*dot of the reference.
// ---------------------------------------------------------------------------
__global__ __launch_bounds__(256) void pack_pos4(
    const float* __restrict__ pos, float4* __restrict__ pos4)
{
    const int i = blockIdx.x * 256 + threadIdx.x;   // 0..8191
    const float* p = pos + (size_t)i * 3;
    const float p0 = p[0], p1 = p[1], p2 = p[2];
    const float pp = __fadd_rn(__fadd_rn(__fmul_rn(p0, p0), __fmul_rn(p1, p1)),
                               __fmul_rn(p2, p2));
    pos4[i] = make_float4(2.0f * p0, 2.0f * p1, 2.0f * p2, pp);
}

// ---------------------------------------------------------------------------
// Kernel B (fused mid): block roles by blockIdx.x:
//   [0,2048)      KNN: 16 queries/block, 16 chunks x 128 cands, single-pass
//                 branchless top-3 (strict < == top_k lowest-index tie-break).
//                 pos4 read from global (L1-resident 32KB/batch). ~7KB LDS ->
//                 8 blocks/CU, 8 waves/SIMD.
//   [2048,6144)   Abig[:,256:384] = bf16(x_skip)
//   [6144,6240)   W1T[n][k] = bf16(W1[k][n])
//   [6240,6272)   W2T[n][k] = bf16(W2[k][n])
//   [6272,6784)   tail: copy pos_skip + synthesize batch_skip into d_out
// ---------------------------------------------------------------------------
__global__ __launch_bounds__(256) void fused_mid(
    const float* __restrict__ x,         // (B*N, CIN)
    const float4* __restrict__ pos4,     // (B*N) packed
    const float* __restrict__ xs,        // (B*M, CSKIP)
    const float* __restrict__ pos_skip,  // (B*M, 3)
    const float* __restrict__ W1, const float* __restrict__ W2,
    ushort* __restrict__ Abig,           // (B*M, KTOT) bf16
    ushort* __restrict__ W1T, ushort* __restrict__ W2T,
    float* __restrict__ tail_dst)        // d_out + B*M*COUT
{
    __shared__ float sPd[16][3][17];
    __shared__ int   sPi[16][3][17];
    __shared__ int   sIdx[16][3];
    __shared__ float sW[16][4];

    const int bid = blockIdx.x;
    const int tid = threadIdx.x;

    if (bid >= 2048) {
        // ---------------- aux roles ----------------
        const int cb = bid - 2048;
        if (cb < 4096) {
            const int q   = cb * 256 + tid;        // quad over 32768x128
            const int row = q >> 5;
            const int cq  = (q & 31) * 4;
            const float4 v = *(const float4*)(xs + (size_t)row * CSKIP + cq);
            ushort4 o; o.x = f2bf(v.x); o.y = f2bf(v.y); o.z = f2bf(v.z); o.w = f2bf(v.w);
            *(ushort4*)(Abig + (size_t)row * KTOT + CIN + cq) = o;
        } else if (cb < 4192) {
            const int q  = (cb - 4096) * 256 + tid;   // 24576 quads: n*96 + kq
            const int n  = q / 96;
            const int kq = (q % 96) * 4;
            ushort4 o;
            o.x = f2bf(W1[(size_t)(kq + 0) * HID + n]);
            o.y = f2bf(W1[(size_t)(kq + 1) * HID + n]);
            o.z = f2bf(W1[(size_t)(kq + 2) * HID + n]);
            o.w = f2bf(W1[(size_t)(kq + 3) * HID + n]);
            *(ushort4*)(W1T + (size_t)n * KTOT + kq) = o;
        } else if (cb < 4224) {
            const int q  = (cb - 4192) * 256 + tid;   // 8192 quads: n*64 + kq
            const int n  = q >> 6;
            const int kq = (q & 63) * 4;
            ushort4 o;
            o.x = f2bf(W2[(size_t)(kq + 0) * COUT + n]);
            o.y = f2bf(W2[(size_t)(kq + 1) * COUT + n]);
            o.z = f2bf(W2[(size_t)(kq + 2) * COUT + n]);
            o.w = f2bf(W2[(size_t)(kq + 3) * COUT + n]);
            *(ushort4*)(W2T + (size_t)n * HID + kq) = o;
        } else {
            const int i = (cb - 4224) * 256 + tid;
            const int nPos = Bn * Mn * 3;             // 98304
            if (i < nPos) tail_dst[i] = pos_skip[i];
            else          tail_dst[i] = (float)((i - nPos) >> 13);
        }
        return;
    }

    // ---------------- KNN role ----------------
    const int qloc   = tid & 15;
    const int chunk  = tid >> 4;         // 0..15, 128 candidates each
    const int blockQ = bid * 16;
    const int b      = blockQ / Mn;      // uniform (512 blocks per batch)

    const int q = blockQ + qloc;
    const float* qp = pos_skip + (size_t)q * 3;
    const float q0 = qp[0], q1 = qp[1], q2 = qp[2];
    const float qq = __fadd_rn(__fadd_rn(__fmul_rn(q0, q0), __fmul_rn(q1, q1)),
                               __fmul_rn(q2, q2));

    const int base = chunk * 128;
    const float4* __restrict__ cp = pos4 + (size_t)b * Nn + base;

    float dA = INFINITY, dB = INFINITY, dC = INFINITY;
    int   iA = 0, iB = 0, iC = 0;
#pragma unroll 4
    for (int j = 0; j < 128; ++j) {
        const float4 P = cp[j];
        const float dot2 = __fadd_rn(__fadd_rn(__fmul_rn(q0, P.x), __fmul_rn(q1, P.y)),
                                     __fmul_rn(q2, P.z));
        const float d = __fsub_rn(__fadd_rn(qq, P.w), dot2);
        const int idx = base + j;
        const bool c1 = d < dA, c2 = d < dB, c3 = d < dC;
        dC = c3 ? (c2 ? dB : d) : dC;  iC = c3 ? (c2 ? iB : idx) : iC;
        dB = c2 ? (c1 ? dA : d) : dB;  iB = c2 ? (c1 ? iA : idx) : iB;
        dA = c1 ? d : dA;              iA = c1 ? idx : iA;
    }
    sPd[chunk][0][qloc] = dA; sPd[chunk][1][qloc] = dB; sPd[chunk][2][qloc] = dC;
    sPi[chunk][0][qloc] = iA; sPi[chunk][1][qloc] = iB; sPi[chunk][2][qloc] = iC;
    __syncthreads();

    // merge 16 partial lists per query (threads 0..15); chunk order = idx order,
    // within-chunk slots d-ascending with lower-idx-first ties -> strict < keeps
    // exactly top_k's value-then-lowest-index order.
    if (tid < 16) {
        float mA = INFINITY, mB = INFINITY, mC = INFINITY;
        int   jA = 0, jB = 0, jC = 0;
#pragma unroll
        for (int c = 0; c < 16; ++c)
#pragma unroll
            for (int s = 0; s < 3; ++s) {
                const float d = sPd[c][s][tid];
                const int   i = sPi[c][s][tid];
                const bool c1 = d < mA, c2 = d < mB, c3 = d < mC;
                mC = c3 ? (c2 ? mB : d) : mC;  jC = c3 ? (c2 ? jB : i) : jC;
                mB = c2 ? (c1 ? mA : d) : mB;  jB = c2 ? (c1 ? jA : i) : jB;
                mA = c1 ? d : mA;              jA = c1 ? i : jA;
            }
        const float w0 = 1.0f / (fmaxf(mA, 0.0f) + 1e-16f);
        const float w1 = 1.0f / (fmaxf(mB, 0.0f) + 1e-16f);
        const float w2 = 1.0f / (fmaxf(mC, 0.0f) + 1e-16f);
        sIdx[tid][0] = jA; sIdx[tid][1] = jB; sIdx[tid][2] = jC;
        sW[tid][0] = w0; sW[tid][1] = w1; sW[tid][2] = w2;
        sW[tid][3] = w0 + w1 + w2;
    }
    __syncthreads();

    // gather: wave w handles queries [w*4, w*4+4); lane covers 4 channels
    const int wave = tid >> 6, lane = tid & 63;
    const size_t xbase = (size_t)b * Nn * CIN;
    for (int j = 0; j < 4; ++j) {
        const int lq = wave * 4 + j;
        const int gq = blockQ + lq;
        const int i0 = sIdx[lq][0], i1 = sIdx[lq][1], i2 = sIdx[lq][2];
        const float w0 = sW[lq][0], w1 = sW[lq][1], w2 = sW[lq][2], den = sW[lq][3];
        const float4 f0 = ((const float4*)(x + xbase + (size_t)i0 * CIN))[lane];
        const float4 f1 = ((const float4*)(x + xbase + (size_t)i1 * CIN))[lane];
        const float4 f2 = ((const float4*)(x + xbase + (size_t)i2 * CIN))[lane];
        ushort4 ov;
        ov.x = f2bf((w0 * f0.x + w1 * f1.x + w2 * f2.x) / den);
        ov.y = f2bf((w0 * f0.y + w1 * f1.y + w2 * f2.y) / den);
        ov.z = f2bf((w0 * f0.z + w1 * f1.z + w2 * f2.z) / den);
        ov.w = f2bf((w0 * f0.w + w1 * f1.w + w2 * f2.w) / den);
        *(ushort4*)(Abig + (size_t)gq * KTOT + lane * 4) = ov;
    }
}

// ---------------------------------------------------------------------------
// Kernel C: fused MLP via bf16 MFMA (32x32x16), f32 accum. (unchanged)
// ---------------------------------------------------------------------------
__global__ __launch_bounds__(256, 1) void mlp_fused(
    const ushort* __restrict__ Abig,   // [32768][384] bf16
    const ushort* __restrict__ W1T,    // [256][384] bf16
    const float*  __restrict__ b1,
    const ushort* __restrict__ W2T,    // [128][256] bf16
    const float*  __restrict__ b2,
    float* __restrict__ out)           // [32768][128] f32
{
    __shared__ ushort Ast[128 * 32];   // 8 KB
    __shared__ ushort Bst[128 * 32];   // 8 KB
    __shared__ ushort Hs [128 * 128];  // 32 KB

    const int tid  = threadIdx.x;
    const int wave = tid >> 6, lane = tid & 63;
    const int wr = wave >> 1, wc = wave & 1;      // 2x2 wave grid
    const int l31 = lane & 31, kc0 = lane >> 5;   // MFMA k-half
    const long rowbase = (long)blockIdx.x * 128;

    const int sr0 = tid >> 2;          // staging row (row+64 for 2nd chunk)
    const int ss0 = tid & 3;           // 16B slot
    const int ssw = (ss0 ^ (sr0 & 3)); // swizzled slot

    f32x16 acc2[2][2];
#pragma unroll
    for (int i = 0; i < 2; ++i)
#pragma unroll
        for (int j = 0; j < 2; ++j)
#pragma unroll
            for (int e = 0; e < 16; ++e) acc2[i][j][e] = 0.0f;

    for (int nh = 0; nh < 2; ++nh) {
        f32x16 acc1[2][2];
#pragma unroll
        for (int i = 0; i < 2; ++i)
#pragma unroll
            for (int j = 0; j < 2; ++j)
#pragma unroll
                for (int e = 0; e < 16; ++e) acc1[i][j][e] = 0.0f;

        const ushort* Ab = Abig + (size_t)rowbase * KTOT;
        const ushort* Wb = W1T + (size_t)(nh * 128) * KTOT;

        uint4 ra0, ra1, rb0, rb1;
        ra0 = *(const uint4*)(Ab + (size_t)sr0 * KTOT + ss0 * 8);
        ra1 = *(const uint4*)(Ab + (size_t)(sr0 + 64) * KTOT + ss0 * 8);
        rb0 = *(const uint4*)(Wb + (size_t)sr0 * KTOT + ss0 * 8);
        rb1 = *(const uint4*)(Wb + (size_t)(sr0 + 64) * KTOT + ss0 * 8);

        for (int t = 0; t < 12; ++t) {
            __syncthreads();
            *(uint4*)&Ast[sr0 * 32 + (ssw << 3)]        = ra0;
            *(uint4*)&Ast[(sr0 + 64) * 32 + (ssw << 3)] = ra1;
            *(uint4*)&Bst[sr0 * 32 + (ssw << 3)]        = rb0;
            *(uint4*)&Bst[(sr0 + 64) * 32 + (ssw << 3)] = rb1;
            __syncthreads();
            if (t < 11) {
                const int kt = (t + 1) * 32;
                ra0 = *(const uint4*)(Ab + (size_t)sr0 * KTOT + kt + ss0 * 8);
                ra1 = *(const uint4*)(Ab + (size_t)(sr0 + 64) * KTOT + kt + ss0 * 8);
                rb0 = *(const uint4*)(Wb + (size_t)sr0 * KTOT + kt + ss0 * 8);
                rb1 = *(const uint4*)(Wb + (size_t)(sr0 + 64) * KTOT + kt + ss0 * 8);
            }
#pragma unroll
            for (int s = 0; s < 2; ++s) {
                bf16x8 af[2], bq[2];
#pragma unroll
                for (int mf = 0; mf < 2; ++mf) {
                    const int r = wr * 64 + mf * 32 + l31;
                    af[mf] = *(const bf16x8*)&Ast[r * 32 + ((((s << 1) | kc0) ^ (r & 3)) << 3)];
                }
#pragma unroll
                for (int nf = 0; nf < 2; ++nf) {
                    const int rn = wc * 64 + nf * 32 + l31;
                    bq[nf] = *(const bf16x8*)&Bst[rn * 32 + ((((s << 1) | kc0) ^ (rn & 3)) << 3)];
                }
#pragma unroll
                for (int mf = 0; mf < 2; ++mf)
#pragma unroll
                    for (int nf = 0; nf < 2; ++nf)
                        acc1[mf][nf] = __builtin_amdgcn_mfma_f32_32x32x16_bf16(
                            af[mf], bq[nf], acc1[mf][nf], 0, 0, 0);
            }
        }

#pragma unroll
        for (int mf = 0; mf < 2; ++mf)
#pragma unroll
            for (int nf = 0; nf < 2; ++nf) {
                const int col = wc * 64 + nf * 32 + l31;
                const float b1v = b1[nh * 128 + col];
#pragma unroll
                for (int e = 0; e < 16; ++e) {
                    const int rl = wr * 64 + mf * 32 + (e & 3) + ((e >> 2) << 3) + (kc0 << 2);
                    const float hv = fmaxf(acc1[mf][nf][e] + b1v, 0.0f);
                    Hs[rl * 128 + (((col >> 3) ^ (rl & 7)) << 3) + (col & 7)] = f2bf(hv);
                }
            }
        __syncthreads();

        uint4 rw0, rw1;
        rw0 = *(const uint4*)(W2T + (size_t)sr0 * HID + nh * 128 + ss0 * 8);
        rw1 = *(const uint4*)(W2T + (size_t)(sr0 + 64) * HID + nh * 128 + ss0 * 8);

        for (int t = 0; t < 4; ++t) {
            __syncthreads();
            *(uint4*)&Bst[sr0 * 32 + (ssw << 3)]        = rw0;
            *(uint4*)&Bst[(sr0 + 64) * 32 + (ssw << 3)] = rw1;
            __syncthreads();
            if (t < 3) {
                const int kt = nh * 128 + (t + 1) * 32;
                rw0 = *(const uint4*)(W2T + (size_t)sr0 * HID + kt + ss0 * 8);
                rw1 = *(const uint4*)(W2T + (size_t)(sr0 + 64) * HID + kt + ss0 * 8);
            }
#pragma unroll
            for (int s = 0; s < 2; ++s) {
                bf16x8 af[2], bq[2];
#pragma unroll
                for (int mf = 0; mf < 2; ++mf) {
                    const int r  = wr * 64 + mf * 32 + l31;
                    const int kc = (t << 2) + (s << 1) + kc0;
                    af[mf] = *(const bf16x8*)&Hs[r * 128 + ((kc ^ (r & 7)) << 3)];
                }
#pragma unroll
                for (int nf = 0; nf < 2; ++nf) {
                    const int rn = wc * 64 + nf * 32 + l31;
                    bq[nf] = *(const bf16x8*)&Bst[rn * 32 + ((((s << 1) | kc0) ^ (rn & 3)) << 3)];
                }
#pragma unroll
                for (int mf = 0; mf < 2; ++mf)
#pragma unroll
                    for (int nf = 0; nf < 2; ++nf)
                        acc2[mf][nf] = __builtin_amdgcn_mfma_f32_32x32x16_bf16(
                            af[mf], bq[nf], acc2[mf][nf], 0, 0, 0);
            }
        }
        __syncthreads();
    }

#pragma unroll
    for (int mf = 0; mf < 2; ++mf)
#pragma unroll
        for (int nf = 0; nf < 2; ++nf) {
            const int col = wc * 64 + nf * 32 + l31;
            const float b2v = b2[col];
#pragma unroll
            for (int e = 0; e < 16; ++e) {
                const int rl = wr * 64 + mf * 32 + (e & 3) + ((e >> 2) << 3) + (kc0 << 2);
                out[(rowbase + rl) * COUT + col] = acc2[mf][nf][e] + b2v;
            }
        }
}

// ---------------------------------------------------------------------------
extern "C" void kernel_launch(void* const* d_in, const int* in_sizes, int n_in,
                              void* d_out, int out_size, void* d_ws, size_t ws_size,
                              hipStream_t stream)
{
    const float* x        = (const float*)d_in[0];
    const float* pos      = (const float*)d_in[1];
    const float* x_skip   = (const float*)d_in[2];
    const float* pos_skip = (const float*)d_in[3];
    const float* W1       = (const float*)d_in[4];
    const float* b1       = (const float*)d_in[5];
    const float* W2       = (const float*)d_in[6];
    const float* b2       = (const float*)d_in[7];

    float* out = (float*)d_out;

    // workspace: Abig (24MB) | W1T (192KB) | W2T (64KB) | pos4 (128KB)
    ushort* Abig = (ushort*)d_ws;
    ushort* W1T  = (ushort*)((char*)d_ws + (size_t)Bn * Mn * KTOT * 2);
    ushort* W2T  = (ushort*)((char*)W1T + (size_t)HID * KTOT * 2);
    float4* pos4 = (float4*)((char*)W2T + (size_t)COUT * HID * 2);

    // A) pack pos -> (2px,2py,2pz,pp)
    pack_pos4<<<dim3(Bn * Nn / 256), 256, 0, stream>>>(pos, pos4);

    // B) KNN (2048 blocks) + x_skip/W1T/W2T converts + tail (4736 blocks)
    fused_mid<<<dim3(2048 + 4736), 256, 0, stream>>>(
        x, pos4, x_skip, pos_skip, W1, W2, Abig, W1T, W2T,
        out + (size_t)Bn * Mn * COUT);

    // C) fused MLP: out = (relu([xi|x_skip] @ W1 + b1)) @ W2 + b2
    mlp_fused<<<dim3(Bn * Mn / 128), 256, 0, stream>>>(
        Abig, W1T, b1, W2T, b2, out);
}

// Round 7
// 78.467 us; speedup vs baseline: 1.0747x; 1.0516x over previous
//
#include <hip/hip_runtime.h>
#include <math.h>
#include <stdint.h>

// Problem constants (FPModule: knn-interpolate + 2-layer MLP)
#define Bn    4
#define Nn    2048
#define Mn    8192
#define CIN   256
#define CSKIP 128
#define HID   256
#define COUT  128
#define KTOT  384   // CIN + CSKIP

typedef short bf16x8 __attribute__((ext_vector_type(8)));
typedef float f32x16 __attribute__((ext_vector_type(16)));

__device__ __forceinline__ ushort f2bf(float f) {
    union { float f; unsigned u; } v; v.f = f;
    return (ushort)((v.u + 0x7fffu + ((v.u >> 16) & 1u)) >> 16);   // RNE
}

// ---------------------------------------------------------------------------
// Kernel A: pack pos -> pos4 = (2px, 2py, 2pz, pp).  8192 points, 32 blocks.
// pp via explicit _rn ops (matches reference); 2x exact so inner-loop dot2 is
// bit-identical to 2*dot of the reference.
// ---------------------------------------------------------------------------
__global__ __launch_bounds__(256) void pack_pos4(
    const float* __restrict__ pos, float4* __restrict__ pos4)
{
    const int i = blockIdx.x * 256 + threadIdx.x;   // 0..8191
    const float* p = pos + (size_t)i * 3;
    const float p0 = p[0], p1 = p[1], p2 = p[2];
    const float pp = __fadd_rn(__fadd_rn(__fmul_rn(p0, p0), __fmul_rn(p1, p1)),
                               __fmul_rn(p2, p2));
    pos4[i] = make_float4(2.0f * p0, 2.0f * p1, 2.0f * p2, pp);
}

// 5-op sorted-insert of key k into (kA <= kB <= kC), keeping 3 smallest.
#define INSERT3(kA, kB, kC, k)            \
    do {                                  \
        const double _t = fmax(kA, k);    \
        kA = fmin(kA, k);                 \
        const double _u = fmax(kB, _t);   \
        kB = fmin(kB, _t);                \
        kC = fmin(kC, _u);                \
    } while (0)

// ---------------------------------------------------------------------------
// Kernel B (fused mid): block roles by blockIdx.x:
//   [0,2048)      KNN: 16 queries/block, 16 chunks x 128 cands. Distance d is
//                 bit-identical to the reference (see pack_pos4). Selection via
//                 f64 key = double(d) with idx in low 11 mantissa bits:
//                 key order == lex (d, idx) == top_k value-then-lowest-index.
//                 Top-3 kept with 5 min/max f64 ops per candidate (no cndmask
//                 network, no index registers).
//   [2048,6144)   Abig[:,256:384] = bf16(x_skip)
//   [6144,6240)   W1T[n][k] = bf16(W1[k][n])
//   [6240,6272)   W2T[n][k] = bf16(W2[k][n])
//   [6272,6784)   tail: copy pos_skip + synthesize batch_skip into d_out
// ---------------------------------------------------------------------------
__global__ __launch_bounds__(256) void fused_mid(
    const float* __restrict__ x,         // (B*N, CIN)
    const float4* __restrict__ pos4,     // (B*N) packed
    const float* __restrict__ xs,        // (B*M, CSKIP)
    const float* __restrict__ pos_skip,  // (B*M, 3)
    const float* __restrict__ W1, const float* __restrict__ W2,
    ushort* __restrict__ Abig,           // (B*M, KTOT) bf16
    ushort* __restrict__ W1T, ushort* __restrict__ W2T,
    float* __restrict__ tail_dst)        // d_out + B*M*COUT
{
    __shared__ double sKey[16][3][17];   // partial top-3 keys (6.5 KB)
    __shared__ int    sIdx[16][3];
    __shared__ float  sRW[16][3];        // premultiplied weights w_i/den

    const int bid = blockIdx.x;
    const int tid = threadIdx.x;

    if (bid >= 2048) {
        // ---------------- aux roles ----------------
        const int cb = bid - 2048;
        if (cb < 4096) {
            const int q   = cb * 256 + tid;        // quad over 32768x128
            const int row = q >> 5;
            const int cq  = (q & 31) * 4;
            const float4 v = *(const float4*)(xs + (size_t)row * CSKIP + cq);
            ushort4 o; o.x = f2bf(v.x); o.y = f2bf(v.y); o.z = f2bf(v.z); o.w = f2bf(v.w);
            *(ushort4*)(Abig + (size_t)row * KTOT + CIN + cq) = o;
        } else if (cb < 4192) {
            const int q  = (cb - 4096) * 256 + tid;   // 24576 quads: n*96 + kq
            const int n  = q / 96;
            const int kq = (q % 96) * 4;
            ushort4 o;
            o.x = f2bf(W1[(size_t)(kq + 0) * HID + n]);
            o.y = f2bf(W1[(size_t)(kq + 1) * HID + n]);
            o.z = f2bf(W1[(size_t)(kq + 2) * HID + n]);
            o.w = f2bf(W1[(size_t)(kq + 3) * HID + n]);
            *(ushort4*)(W1T + (size_t)n * KTOT + kq) = o;
        } else if (cb < 4224) {
            const int q  = (cb - 4192) * 256 + tid;   // 8192 quads: n*64 + kq
            const int n  = q >> 6;
            const int kq = (q & 63) * 4;
            ushort4 o;
            o.x = f2bf(W2[(size_t)(kq + 0) * COUT + n]);
            o.y = f2bf(W2[(size_t)(kq + 1) * COUT + n]);
            o.z = f2bf(W2[(size_t)(kq + 2) * COUT + n]);
            o.w = f2bf(W2[(size_t)(kq + 3) * COUT + n]);
            *(ushort4*)(W2T + (size_t)n * HID + kq) = o;
        } else {
            const int i = (cb - 4224) * 256 + tid;
            const int nPos = Bn * Mn * 3;             // 98304
            if (i < nPos) tail_dst[i] = pos_skip[i];
            else          tail_dst[i] = (float)((i - nPos) >> 13);
        }
        return;
    }

    // ---------------- KNN role ----------------
    const int qloc   = tid & 15;
    const int chunk  = tid >> 4;         // 0..15, 128 candidates each
    const int blockQ = bid * 16;
    const int b      = blockQ / Mn;      // uniform (512 blocks per batch)

    const int q = blockQ + qloc;
    const float* qp = pos_skip + (size_t)q * 3;
    const float q0 = qp[0], q1 = qp[1], q2 = qp[2];
    const float qq = __fadd_rn(__fadd_rn(__fmul_rn(q0, q0), __fmul_rn(q1, q1)),
                               __fmul_rn(q2, q2));

    const int base = chunk * 128;
    const float4* __restrict__ cp = pos4 + (size_t)b * Nn + base;

    double kA = INFINITY, kB = INFINITY, kC = INFINITY;
#pragma unroll 4
    for (int j = 0; j < 128; ++j) {
        const float4 P = cp[j];
        const float dot2 = __fadd_rn(__fadd_rn(__fmul_rn(q0, P.x), __fmul_rn(q1, P.y)),
                                     __fmul_rn(q2, P.z));
        const float d = __fsub_rn(__fadd_rn(qq, P.w), dot2);
        const double k = __longlong_as_double(
            __double_as_longlong((double)d) | (long long)(base + j));
        INSERT3(kA, kB, kC, k);
    }
    sKey[chunk][0][qloc] = kA;
    sKey[chunk][1][qloc] = kB;
    sKey[chunk][2][qloc] = kC;
    __syncthreads();

    // merge 16 partial triples per query (threads 0..15) with the same network
    if (tid < 16) {
        double mA = INFINITY, mB = INFINITY, mC = INFINITY;
#pragma unroll
        for (int c = 0; c < 16; ++c)
#pragma unroll
            for (int s = 0; s < 3; ++s) {
                const double k = sKey[c][s][tid];
                INSERT3(mA, mB, mC, k);
            }
        // unpack: idx = low 11 bits; exact d = key with idx bits cleared
        const long long ba = __double_as_longlong(mA);
        const long long bb = __double_as_longlong(mB);
        const long long bc = __double_as_longlong(mC);
        const float dA = (float)__longlong_as_double(ba & ~0x7FFll);
        const float dB = (float)__longlong_as_double(bb & ~0x7FFll);
        const float dC = (float)__longlong_as_double(bc & ~0x7FFll);
        const float w0 = 1.0f / (fmaxf(dA, 0.0f) + 1e-16f);
        const float w1 = 1.0f / (fmaxf(dB, 0.0f) + 1e-16f);
        const float w2 = 1.0f / (fmaxf(dC, 0.0f) + 1e-16f);
        const float rden = 1.0f / (w0 + w1 + w2);
        sIdx[tid][0] = (int)(ba & 0x7FF);
        sIdx[tid][1] = (int)(bb & 0x7FF);
        sIdx[tid][2] = (int)(bc & 0x7FF);
        sRW[tid][0] = w0 * rden; sRW[tid][1] = w1 * rden; sRW[tid][2] = w2 * rden;
    }
    __syncthreads();

    // gather: wave w handles queries [w*4, w*4+4); lane covers 4 channels
    const int wave = tid >> 6, lane = tid & 63;
    const size_t xbase = (size_t)b * Nn * CIN;
    for (int j = 0; j < 4; ++j) {
        const int lq = wave * 4 + j;
        const int gq = blockQ + lq;
        const int i0 = sIdx[lq][0], i1 = sIdx[lq][1], i2 = sIdx[lq][2];
        const float w0 = sRW[lq][0], w1 = sRW[lq][1], w2 = sRW[lq][2];
        const float4 f0 = ((const float4*)(x + xbase + (size_t)i0 * CIN))[lane];
        const float4 f1 = ((const float4*)(x + xbase + (size_t)i1 * CIN))[lane];
        const float4 f2 = ((const float4*)(x + xbase + (size_t)i2 * CIN))[lane];
        ushort4 ov;
        ov.x = f2bf(fmaf(w2, f2.x, fmaf(w1, f1.x, w0 * f0.x)));
        ov.y = f2bf(fmaf(w2, f2.y, fmaf(w1, f1.y, w0 * f0.y)));
        ov.z = f2bf(fmaf(w2, f2.z, fmaf(w1, f1.z, w0 * f0.z)));
        ov.w = f2bf(fmaf(w2, f2.w, fmaf(w1, f1.w, w0 * f0.w)));
        *(ushort4*)(Abig + (size_t)gq * KTOT + lane * 4) = ov;
    }
}

// ---------------------------------------------------------------------------
// Kernel C: fused MLP via bf16 MFMA (32x32x16), f32 accum. (unchanged)
// ---------------------------------------------------------------------------
__global__ __launch_bounds__(256, 1) void mlp_fused(
    const ushort* __restrict__ Abig,   // [32768][384] bf16
    const ushort* __restrict__ W1T,    // [256][384] bf16
    const float*  __restrict__ b1,
    const ushort* __restrict__ W2T,    // [128][256] bf16
    const float*  __restrict__ b2,
    float* __restrict__ out)           // [32768][128] f32
{
    __shared__ ushort Ast[128 * 32];   // 8 KB
    __shared__ ushort Bst[128 * 32];   // 8 KB
    __shared__ ushort Hs [128 * 128];  // 32 KB

    const int tid  = threadIdx.x;
    const int wave = tid >> 6, lane = tid & 63;
    const int wr = wave >> 1, wc = wave & 1;      // 2x2 wave grid
    const int l31 = lane & 31, kc0 = lane >> 5;   // MFMA k-half
    const long rowbase = (long)blockIdx.x * 128;

    const int sr0 = tid >> 2;          // staging row (row+64 for 2nd chunk)
    const int ss0 = tid & 3;           // 16B slot
    const int ssw = (ss0 ^ (sr0 & 3)); // swizzled slot

    f32x16 acc2[2][2];
#pragma unroll
    for (int i = 0; i < 2; ++i)
#pragma unroll
        for (int j = 0; j < 2; ++j)
#pragma unroll
            for (int e = 0; e < 16; ++e) acc2[i][j][e] = 0.0f;

    for (int nh = 0; nh < 2; ++nh) {
        f32x16 acc1[2][2];
#pragma unroll
        for (int i = 0; i < 2; ++i)
#pragma unroll
            for (int j = 0; j < 2; ++j)
#pragma unroll
                for (int e = 0; e < 16; ++e) acc1[i][j][e] = 0.0f;

        const ushort* Ab = Abig + (size_t)rowbase * KTOT;
        const ushort* Wb = W1T + (size_t)(nh * 128) * KTOT;

        uint4 ra0, ra1, rb0, rb1;
        ra0 = *(const uint4*)(Ab + (size_t)sr0 * KTOT + ss0 * 8);
        ra1 = *(const uint4*)(Ab + (size_t)(sr0 + 64) * KTOT + ss0 * 8);
        rb0 = *(const uint4*)(Wb + (size_t)sr0 * KTOT + ss0 * 8);
        rb1 = *(const uint4*)(Wb + (size_t)(sr0 + 64) * KTOT + ss0 * 8);

        for (int t = 0; t < 12; ++t) {
            __syncthreads();
            *(uint4*)&Ast[sr0 * 32 + (ssw << 3)]        = ra0;
            *(uint4*)&Ast[(sr0 + 64) * 32 + (ssw << 3)] = ra1;
            *(uint4*)&Bst[sr0 * 32 + (ssw << 3)]        = rb0;
            *(uint4*)&Bst[(sr0 + 64) * 32 + (ssw << 3)] = rb1;
            __syncthreads();
            if (t < 11) {
                const int kt = (t + 1) * 32;
                ra0 = *(const uint4*)(Ab + (size_t)sr0 * KTOT + kt + ss0 * 8);
                ra1 = *(const uint4*)(Ab + (size_t)(sr0 + 64) * KTOT + kt + ss0 * 8);
                rb0 = *(const uint4*)(Wb + (size_t)sr0 * KTOT + kt + ss0 * 8);
                rb1 = *(const uint4*)(Wb + (size_t)(sr0 + 64) * KTOT + kt + ss0 * 8);
            }
#pragma unroll
            for (int s = 0; s < 2; ++s) {
                bf16x8 af[2], bq[2];
#pragma unroll
                for (int mf = 0; mf < 2; ++mf) {
                    const int r = wr * 64 + mf * 32 + l31;
                    af[mf] = *(const bf16x8*)&Ast[r * 32 + ((((s << 1) | kc0) ^ (r & 3)) << 3)];
                }
#pragma unroll
                for (int nf = 0; nf < 2; ++nf) {
                    const int rn = wc * 64 + nf * 32 + l31;
                    bq[nf] = *(const bf16x8*)&Bst[rn * 32 + ((((s << 1) | kc0) ^ (rn & 3)) << 3)];
                }
#pragma unroll
                for (int mf = 0; mf < 2; ++mf)
#pragma unroll
                    for (int nf = 0; nf < 2; ++nf)
                        acc1[mf][nf] = __builtin_amdgcn_mfma_f32_32x32x16_bf16(
                            af[mf], bq[nf], acc1[mf][nf], 0, 0, 0);
            }
        }

#pragma unroll
        for (int mf = 0; mf < 2; ++mf)
#pragma unroll
            for (int nf = 0; nf < 2; ++nf) {
                const int col = wc * 64 + nf * 32 + l31;
                const float b1v = b1[nh * 128 + col];
#pragma unroll
                for (int e = 0; e < 16; ++e) {
                    const int rl = wr * 64 + mf * 32 + (e & 3) + ((e >> 2) << 3) + (kc0 << 2);
                    const float hv = fmaxf(acc1[mf][nf][e] + b1v, 0.0f);
                    Hs[rl * 128 + (((col >> 3) ^ (rl & 7)) << 3) + (col & 7)] = f2bf(hv);
                }
            }
        __syncthreads();

        uint4 rw0, rw1;
        rw0 = *(const uint4*)(W2T + (size_t)sr0 * HID + nh * 128 + ss0 * 8);
        rw1 = *(const uint4*)(W2T + (size_t)(sr0 + 64) * HID + nh * 128 + ss0 * 8);

        for (int t = 0; t < 4; ++t) {
            __syncthreads();
            *(uint4*)&Bst[sr0 * 32 + (ssw << 3)]        = rw0;
            *(uint4*)&Bst[(sr0 + 64) * 32 + (ssw << 3)] = rw1;
            __syncthreads();
            if (t < 3) {
                const int kt = nh * 128 + (t + 1) * 32;
                rw0 = *(const uint4*)(W2T + (size_t)sr0 * HID + kt + ss0 * 8);
                rw1 = *(const uint4*)(W2T + (size_t)(sr0 + 64) * HID + kt + ss0 * 8);
            }
#pragma unroll
            for (int s = 0; s < 2; ++s) {
                bf16x8 af[2], bq[2];
#pragma unroll
                for (int mf = 0; mf < 2; ++mf) {
                    const int r  = wr * 64 + mf * 32 + l31;
                    const int kc = (t << 2) + (s << 1) + kc0;
                    af[mf] = *(const bf16x8*)&Hs[r * 128 + ((kc ^ (r & 7)) << 3)];
                }
#pragma unroll
                for (int nf = 0; nf < 2; ++nf) {
                    const int rn = wc * 64 + nf * 32 + l31;
                    bq[nf] = *(const bf16x8*)&Bst[rn * 32 + ((((s << 1) | kc0) ^ (rn & 3)) << 3)];
                }
#pragma unroll
                for (int mf = 0; mf < 2; ++mf)
#pragma unroll
                    for (int nf = 0; nf < 2; ++nf)
                        acc2[mf][nf] = __builtin_amdgcn_mfma_f32_32x32x16_bf16(
                            af[mf], bq[nf], acc2[mf][nf], 0, 0, 0);
            }
        }
        __syncthreads();
    }

#pragma unroll
    for (int mf = 0; mf < 2; ++mf)
#pragma unroll
        for (int nf = 0; nf < 2; ++nf) {
            const int col = wc * 64 + nf * 32 + l31;
            const float b2v = b2[col];
#pragma unroll
            for (int e = 0; e < 16; ++e) {
                const int rl = wr * 64 + mf * 32 + (e & 3) + ((e >> 2) << 3) + (kc0 << 2);
                out[(rowbase + rl) * COUT + col] = acc2[mf][nf][e] + b2v;
            }
        }
}

// ---------------------------------------------------------------------------
extern "C" void kernel_launch(void* const* d_in, const int* in_sizes, int n_in,
                              void* d_out, int out_size, void* d_ws, size_t ws_size,
                              hipStream_t stream)
{
    const float* x        = (const float*)d_in[0];
    const float* pos      = (const float*)d_in[1];
    const float* x_skip   = (const float*)d_in[2];
    const float* pos_skip = (const float*)d_in[3];
    const float* W1       = (const float*)d_in[4];
    const float* b1       = (const float*)d_in[5];
    const float* W2       = (const float*)d_in[6];
    const float* b2       = (const float*)d_in[7];

    float* out = (float*)d_out;

    // workspace: Abig (24MB) | W1T (192KB) | W2T (64KB) | pos4 (128KB)
    ushort* Abig = (ushort*)d_ws;
    ushort* W1T  = (ushort*)((char*)d_ws + (size_t)Bn * Mn * KTOT * 2);
    ushort* W2T  = (ushort*)((char*)W1T + (size_t)HID * KTOT * 2);
    float4* pos4 = (float4*)((char*)W2T + (size_t)COUT * HID * 2);

    // A) pack pos -> (2px,2py,2pz,pp)
    pack_pos4<<<dim3(Bn * Nn / 256), 256, 0, stream>>>(pos, pos4);

    // B) KNN (2048 blocks) + x_skip/W1T/W2T converts + tail (4736 blocks)
    fused_mid<<<dim3(2048 + 4736), 256, 0, stream>>>(
        x, pos4, x_skip, pos_skip, W1, W2, Abig, W1T, W2T,
        out + (size_t)Bn * Mn * COUT);

    // C) fused MLP: out = (relu([xi|x_skip] @ W1 + b1)) @ W2 + b2
    mlp_fused<<<dim3(Bn * Mn / 128), 256, 0, stream>>>(
        Abig, W1T, b1, W2T, b2, out);
}